// Round 3
// baseline (283.003 us; speedup 1.0000x reference)
//
#include <hip/hip_runtime.h>
#include <stdint.h>

// ---------------------------------------------------------------------------
// PDG2Seq_GCN: B=16, N=1024, C=O=64, D=10, CHEB_K=2 (K=5 stacked terms)
// Round 3:
//  - hop kernel: barrier-free K-loop. A staged into WAVE-PRIVATE LDS via
//    global_load_lds, synced with per-wave s_waitcnt vmcnt(N) (no
//    __syncthreads in the loop -> loads stay in flight across stages).
//    B fragments load straight to registers (XT slice is L2-hot).
//  - hop2 runs in REVERSED slice/tile order to hit hop1's LLC-resident adj.
//  - wgen moved after hops so WT is LLC-hot for final; final 2x parallelism.
// ---------------------------------------------------------------------------

typedef __attribute__((ext_vector_type(4))) float f32x4;
typedef __attribute__((ext_vector_type(2))) float f32x2;
typedef __attribute__((ext_vector_type(8))) short s16x8;
typedef __attribute__((ext_vector_type(8))) __bf16 bf16x8;

__device__ __forceinline__ unsigned short f2bf(float f) {
  union { float f; uint32_t u; } v; v.f = f;
  uint32_t r = v.u + 0x7FFFu + ((v.u >> 16) & 1u);   // RNE
  return (unsigned short)(r >> 16);
}
__device__ __forceinline__ uint32_t pack2(float a, float b) {
  return (uint32_t)f2bf(a) | ((uint32_t)f2bf(b) << 16);
}

union FragU { s16x8 s; bf16x8 b; };

__device__ __forceinline__ void async_cp16(const void* g, void* l) {
  __builtin_amdgcn_global_load_lds(
      (const __attribute__((address_space(1))) void*)g,
      (__attribute__((address_space(3))) void*)l, 16, 0, 0);
}

// s_waitcnt with only vmcnt constrained (expcnt=7, lgkmcnt=15 -> no wait)
#define WAITVM(n)                                                         \
  __builtin_amdgcn_s_waitcnt(((n) & 15) | ((((n) >> 4) & 3) << 14) |      \
                             (7 << 4) | (15 << 8))

// ---------------------------------------------------------------------------
// K0a: x [16][1024][64] f32  ->  XT0 [16][64][1024] bf16
// ---------------------------------------------------------------------------
__global__ void transpose_x(const float* __restrict__ x,
                            unsigned short* __restrict__ XT0) {
  __shared__ unsigned short tl[64][72];
  const int b = blockIdx.y, n0 = blockIdx.x * 64;
  const int tid = threadIdx.x;
  {
    const int c4 = (tid & 15) * 4;
#pragma unroll
    for (int i = 0; i < 4; ++i) {
      const int row = (tid >> 4) + i * 16;
      f32x4 v = *(const f32x4*)(x + ((size_t)(b * 1024 + n0 + row)) * 64 + c4);
      *(uint32_t*)&tl[row][c4]     = pack2(v[0], v[1]);
      *(uint32_t*)&tl[row][c4 + 2] = pack2(v[2], v[3]);
    }
  }
  __syncthreads();
  {
    const int c = tid >> 2;
    const int nch = (tid & 3) * 16;
    s16x8 s0, s1;
#pragma unroll
    for (int j = 0; j < 8; ++j) {
      s0[j] = (short)tl[nch + j][c];
      s1[j] = (short)tl[nch + 8 + j][c];
    }
    unsigned short* p = XT0 + (size_t)(b * 64 + c) * 1024 + n0 + nch;
    *(s16x8*)p = s0;
    *(s16x8*)(p + 8) = s1;
  }
}

// ---------------------------------------------------------------------------
// K0b: wp [10][320][64] -> wpT [10][64][320] f32
// ---------------------------------------------------------------------------
__global__ void transpose_wp(const float* __restrict__ wp,
                             float* __restrict__ wpT) {
  __shared__ float tl[64][65];
  const int d = blockIdx.y;
  const int ki0 = blockIdx.x * 64;
  const int tid = threadIdx.x;
  const float* src = wp + (size_t)d * 20480;
  {
    const int o4 = (tid & 15) * 4;
#pragma unroll
    for (int i = 0; i < 4; ++i) {
      const int row = (tid >> 4) + i * 16;
      f32x4 v = *(const f32x4*)(src + (size_t)(ki0 + row) * 64 + o4);
      tl[row][o4] = v[0]; tl[row][o4 + 1] = v[1];
      tl[row][o4 + 2] = v[2]; tl[row][o4 + 3] = v[3];
    }
  }
  __syncthreads();
  {
    const int o = tid >> 2;
    const int kch = (tid & 3) * 16;
    float* dst = wpT + (size_t)d * 20480 + (size_t)o * 320 + ki0 + kch;
#pragma unroll
    for (int u = 0; u < 4; ++u) {
      f32x4 v = { tl[kch + 4 * u][o], tl[kch + 4 * u + 1][o],
                  tl[kch + 4 * u + 2][o], tl[kch + 4 * u + 3][o] };
      *(f32x4*)(dst + 4 * u) = v;
    }
  }
}

// ---------------------------------------------------------------------------
// K4: WT[n][o][ki] bf16 = sum_d emb[n,d] * wpT[d][o][ki]
// ---------------------------------------------------------------------------
__global__ __launch_bounds__(256) void wgen(const float* __restrict__ wpT,
                                            const float* __restrict__ emb,
                                            unsigned short* __restrict__ WT) {
  const int idx = (blockIdx.x * 256 + threadIdx.x) * 2;   // 0..20478
  const int n0 = blockIdx.y * 16;
  f32x2 wv[10];
#pragma unroll
  for (int d = 0; d < 10; ++d)
    wv[d] = *(const f32x2*)(wpT + (size_t)d * 20480 + idx);
#pragma unroll
  for (int g = 0; g < 16; ++g) {
    float a0 = 0.f, a1 = 0.f;
#pragma unroll
    for (int d = 0; d < 10; ++d) {
      const float e = emb[(n0 + g) * 10 + d];
      a0 += e * wv[d][0];
      a1 += e * wv[d][1];
    }
    *(uint32_t*)(WT + (size_t)(n0 + g) * 20480 + idx) = pack2(a0, a1);
  }
}

// ---------------------------------------------------------------------------
// K2/K3: hop GEMM, barrier-free pipelined K-loop.
// Block 256 = 4 waves; wave owns 16 rows x 64 cols. BK=64, 2-deep pipeline.
// Per stage per wave: 4x global_load_lds (A, 16B/lane, XOR-chunk-swizzled
// source so fragment ds_read_b128 is <=2-way bank aliased) + 8x 16B global
// loads (B fragments, registers). 12 vm ops/stage -> WAITVM(12)/WAITVM(0).
// grid (16 row-tiles, 32 slices).
// ---------------------------------------------------------------------------
__global__ __launch_bounds__(256, 2) void hop_kernel(
    const float* __restrict__ adj, const unsigned short* __restrict__ XTin,
    float* __restrict__ Xout, unsigned short* __restrict__ XTout,
    int xt_shared, int write_xt, int rev) {
  __shared__ __align__(16) char smem[32768];   // 4 waves x 2 stages x 4 KB
  const int bx = rev ? (15 - (int)blockIdx.x) : (int)blockIdx.x;
  const int slice = rev ? (31 - (int)blockIdx.y) : (int)blockIdx.y;
  const int b = slice & 15;
  const float* __restrict__ A = adj + (size_t)slice * (1024u * 1024u);
  const unsigned short* __restrict__ XT =
      XTin + (size_t)(xt_shared ? b : slice) * (64 * 1024);
  const int tid = threadIdx.x;
  const int wave = tid >> 6, lane = tid & 63;
  const int l15 = lane & 15, q = lane >> 4;
  const int rowbase = bx * 64;

  float* const Abase = (float*)smem + wave * 2048;   // 2 stages x 1024 f32

  // A staging source addresses (4 DMA instrs, lane -> 16B chunk)
  const float* ag[4];
#pragma unroll
  for (int i = 0; i < 4; ++i) {
    const int wl = i * 4 + (lane >> 4);              // wave-local row 0..15
    const int ch = (lane & 15) ^ (wl & 7);           // swizzled 4-float chunk
    ag[i] = A + (size_t)(rowbase + wave * 16 + wl) * 1024 + ch * 4;
  }
  // B fragment source addresses (8 register loads per stage)
  const unsigned short* bg[8];
#pragma unroll
  for (int t = 0; t < 4; ++t)
#pragma unroll
    for (int h = 0; h < 2; ++h)
      bg[t * 2 + h] = XT + (size_t)(t * 16 + l15) * 1024 + h * 32 + q * 8;

  f32x4 acc[4];
#pragma unroll
  for (int t = 0; t < 4; ++t) acc[t] = (f32x4){0.f, 0.f, 0.f, 0.f};

  s16x8 breg0[8], breg1[8];

  auto issueA = [&](int k0, int s) {
#pragma unroll
    for (int i = 0; i < 4; ++i)
      async_cp16(ag[i] + k0, Abase + s * 1024 + i * 256);
  };
  auto issueB = [&](int k0, s16x8 (&br)[8]) {
#pragma unroll
    for (int j = 0; j < 8; ++j) br[j] = *(const s16x8*)(bg[j] + k0);
  };
  auto compute = [&](int s, const s16x8 (&br)[8]) {
    const float* Ab = Abase + s * 1024;
    const int sw = l15 & 7;
#pragma unroll
    for (int h = 0; h < 2; ++h) {
      const int j0 = h * 8 + q * 2;
      f32x4 c0 = *(const f32x4*)(Ab + l15 * 64 + (j0 ^ sw) * 4);
      f32x4 c1 = *(const f32x4*)(Ab + l15 * 64 + ((j0 + 1) ^ sw) * 4);
      FragU af;
#pragma unroll
      for (int e = 0; e < 4; ++e) {
        af.s[e]     = (short)f2bf(c0[e]);
        af.s[e + 4] = (short)f2bf(c1[e]);
      }
#pragma unroll
      for (int t = 0; t < 4; ++t) {
        FragU bf; bf.s = br[t * 2 + h];
        acc[t] = __builtin_amdgcn_mfma_f32_16x16x32_bf16(af.b, bf.b, acc[t],
                                                         0, 0, 0);
      }
    }
  };

  issueA(0, 0);    issueB(0, breg0);       // stage 0 -> 12 vm ops
  issueA(64, 1);   issueB(64, breg1);      // stage 1 -> 24 outstanding
#pragma unroll 1
  for (int kt = 0; kt < 14; kt += 2) {
    WAITVM(12);                            // stage kt arrived
    compute(0, breg0);
    issueA((kt + 2) * 64, 0); issueB((kt + 2) * 64, breg0);
    WAITVM(12);                            // stage kt+1 arrived
    compute(1, breg1);
    issueA((kt + 3) * 64, 1); issueB((kt + 3) * 64, breg1);
  }
  WAITVM(12);
  compute(0, breg0);                       // stage 14
  WAITVM(0);
  compute(1, breg1);                       // stage 15

  // Epilogue: transpose via LDS (reuse stage memory)
  __syncthreads();
  float (*tile)[65] = (float(*)[65])smem;
#pragma unroll
  for (int t = 0; t < 4; ++t)
#pragma unroll
    for (int rr = 0; rr < 4; ++rr)
      tile[wave * 16 + q * 4 + rr][t * 16 + l15] = acc[t][rr];
  __syncthreads();

  {
    const int row = tid >> 2;
    const int cb = (tid & 3) * 16;
    float* __restrict__ outp = Xout + (size_t)slice * (1024 * 64) +
                               (size_t)(rowbase + row) * 64 + cb;
#pragma unroll
    for (int u = 0; u < 4; ++u) {
      f32x4 v = { tile[row][cb + 4 * u], tile[row][cb + 4 * u + 1],
                  tile[row][cb + 4 * u + 2], tile[row][cb + 4 * u + 3] };
      *(f32x4*)(outp + 4 * u) = v;
    }
  }
  if (write_xt) {
    const int c = tid >> 2;
    const int nch = (tid & 3) * 16;
    unsigned short* __restrict__ xtp = XTout + (size_t)slice * (64 * 1024) +
                                       (size_t)c * 1024 + rowbase + nch;
    s16x8 s0, s1;
#pragma unroll
    for (int j = 0; j < 8; ++j) {
      s0[j] = (short)f2bf(tile[nch + j][c]);
      s1[j] = (short)f2bf(tile[nch + 8 + j][c]);
    }
    *(s16x8*)xtp = s0;
    *(s16x8*)(xtp + 8) = s1;
  }
}

// ---------------------------------------------------------------------------
// K5: out[b,n,o] = Xg[b,n,:] (320) @ W_n[320,64] + bias[n,o]
// 2 nodes/block, 2 waves per node (o-halves). grid 512, block 256.
// ---------------------------------------------------------------------------
__global__ __launch_bounds__(256, 2) void final_kernel(
    const float* __restrict__ x, const float* __restrict__ X1,
    const float* __restrict__ X2, const unsigned short* __restrict__ WT,
    const float* __restrict__ emb, const float* __restrict__ bias_pool,
    float* __restrict__ out) {
  __shared__ unsigned short xg[2][16][328];
  const int tid = threadIdx.x;
  const int node_base = blockIdx.x * 2;

  for (int u = tid; u < 5120; u += 256) {       // units of 2 ki
    const int nd = u / 2560;
    int rem = u - nd * 2560;
    const int bb = rem / 160;
    const int kiu = rem - bb * 160;
    const int ki = kiu * 2;
    const int k = ki >> 6;
    const int c = ki & 63;
    const int nn = node_base + nd;
    const float* src;
    if (k == 0) {
      src = x + ((size_t)bb * 1024 + nn) * 64 + c;
    } else {
      const float* arr = (k == 1 || k == 3) ? X1 : X2;
      const int s = (k >= 3) ? 1 : 0;
      src = arr + ((size_t)(s * 16 + bb) * 1024 + nn) * 64 + c;
    }
    f32x2 v = *(const f32x2*)src;
    *(uint32_t*)&xg[nd][bb][ki] = pack2(v[0], v[1]);
  }
  __syncthreads();

  const int wave = tid >> 6, lane = tid & 63;
  const int nd = wave >> 1, oh = wave & 1;
  const int l15 = lane & 15, q = lane >> 4;
  const int n = node_base + nd;
  f32x4 acc[2];
#pragma unroll
  for (int t = 0; t < 2; ++t) acc[t] = (f32x4){0.f, 0.f, 0.f, 0.f};

  const unsigned short* wt0 =
      WT + (size_t)n * 20480 + (size_t)l15 * 320 + q * 8;
#pragma unroll
  for (int ks = 0; ks < 10; ++ks) {
    const int k0 = ks * 32;
    FragU af;
    af.s = *(const s16x8*)&xg[nd][l15][k0 + q * 8];
#pragma unroll
    for (int tt = 0; tt < 2; ++tt) {
      const int t = oh * 2 + tt;
      FragU bf;
      bf.s = *(const s16x8*)(wt0 + (size_t)t * (16 * 320) + k0);
      acc[tt] = __builtin_amdgcn_mfma_f32_16x16x32_bf16(af.b, bf.b, acc[tt],
                                                        0, 0, 0);
    }
  }

#pragma unroll
  for (int tt = 0; tt < 2; ++tt) {
    const int o = (oh * 2 + tt) * 16 + l15;
    float bv = 0.f;
#pragma unroll
    for (int d = 0; d < 10; ++d)
      bv += emb[n * 10 + d] * bias_pool[d * 64 + o];
#pragma unroll
    for (int rr = 0; rr < 4; ++rr) {
      const int bb = q * 4 + rr;
      out[((size_t)bb * 1024 + n) * 64 + o] = acc[tt][rr] + bv;
    }
  }
}

// ---------------------------------------------------------------------------
extern "C" void kernel_launch(void* const* d_in, const int* in_sizes, int n_in,
                              void* d_out, int out_size, void* d_ws,
                              size_t ws_size, hipStream_t stream) {
  const float* x   = (const float*)d_in[0];   // [16,1024,64]
  const float* adj = (const float*)d_in[1];   // [2,16,1024,1024]
  const float* emb = (const float*)d_in[2];   // [1024,10]
  const float* wp  = (const float*)d_in[3];   // [10,5,64,64]
  const float* bp  = (const float*)d_in[4];   // [10,64]
  float* out = (float*)d_out;                 // [16,1024,64]

  char* ws = (char*)d_ws;
  unsigned short* XT0 = (unsigned short*)(ws);                     // 2 MB
  unsigned short* XT1 = (unsigned short*)(ws + ((size_t)2 << 20)); // 4 MB
  float* X1  = (float*)(ws + ((size_t)6 << 20));                   // 8 MB
  float* X2  = (float*)(ws + ((size_t)14 << 20));                  // 8 MB
  float* wpT = (float*)(ws + ((size_t)22 << 20));                  // 0.82 MB
  unsigned short* WT = (unsigned short*)(ws + ((size_t)23 << 20)); // 40 MB

  transpose_x<<<dim3(16, 16), dim3(256), 0, stream>>>(x, XT0);
  hop_kernel<<<dim3(16, 32), dim3(256), 0, stream>>>(adj, XT0, X1, XT1,
                                                     1, 1, 0);
  hop_kernel<<<dim3(16, 32), dim3(256), 0, stream>>>(adj, XT1, X2,
                                                     (unsigned short*)nullptr,
                                                     0, 0, 1);
  transpose_wp<<<dim3(5, 10), dim3(256), 0, stream>>>(wp, wpT);
  wgen<<<dim3(40, 64), dim3(256), 0, stream>>>(wpT, emb, WT);
  final_kernel<<<dim3(512), dim3(256), 0, stream>>>(x, X1, X2, WT, emb, bp,
                                                    out);
}